// Round 1
// baseline (1938.874 us; speedup 1.0000x reference)
//
#include <hip/hip_runtime.h>

#define BB 4
#define SS 2048
#define DD 1024
#define EE 8
#define HH 2048
#define NTOK (BB*SS)   // 8192 tokens
#define TOT  (NTOK*2)  // 16384 token-slots (top-2)

typedef unsigned short u16;
typedef float f32x4 __attribute__((ext_vector_type(4)));
typedef u16   u16x8 __attribute__((ext_vector_type(8)));

__device__ inline u16 f2bf(float f) {
    union { float f; unsigned u; } v; v.f = f;
    unsigned r = v.u + 0x7FFFu + ((v.u >> 16) & 1u);   // RNE
    return (u16)(r >> 16);
}

__device__ inline void mfma_16x16x32(f32x4& c, u16x8 a, u16x8 b) {
    // D = A*B + C, C/D in VGPRs (gfx950 unified file). Inline asm avoids
    // builtin operand-type (V8y vs V8s) compile risk.
    asm("v_mfma_f32_16x16x32_bf16 %0, %1, %2, %0" : "+v"(c) : "v"(a), "v"(b));
}

// ---------------- router: fp32 logits, softmax, top-2, renorm ----------------
__global__ __launch_bounds__(256) void router_kernel(
    const float* __restrict__ x, const float* __restrict__ Wr,
    const float* __restrict__ br, int* __restrict__ tk_e,
    float* __restrict__ tk_w, int* __restrict__ counts)
{
    int wave = threadIdx.x >> 6, lane = threadIdx.x & 63;
    int t = blockIdx.x * 4 + wave;
    const float* xr = x + (size_t)t * DD;
    float acc[8];
    #pragma unroll
    for (int e = 0; e < 8; e++) acc[e] = 0.f;
    #pragma unroll
    for (int c = 0; c < 4; c++) {
        float4 v = *(const float4*)(xr + c * 256 + lane * 4);
        int dbase = c * 256 + lane * 4;
        #pragma unroll
        for (int q = 0; q < 4; q++) {
            float xv = (q == 0) ? v.x : (q == 1) ? v.y : (q == 2) ? v.z : v.w;
            const float4* wr = (const float4*)(Wr + (size_t)(dbase + q) * 8);
            float4 w0 = wr[0], w1 = wr[1];
            acc[0] += xv * w0.x; acc[1] += xv * w0.y;
            acc[2] += xv * w0.z; acc[3] += xv * w0.w;
            acc[4] += xv * w1.x; acc[5] += xv * w1.y;
            acc[6] += xv * w1.z; acc[7] += xv * w1.w;
        }
    }
    #pragma unroll
    for (int off = 32; off > 0; off >>= 1)
        #pragma unroll
        for (int e = 0; e < 8; e++) acc[e] += __shfl_xor(acc[e], off, 64);

    if (lane == 0) {
        float l[8], p[8];
        #pragma unroll
        for (int e = 0; e < 8; e++) l[e] = acc[e] + br[e];
        float mx = l[0];
        #pragma unroll
        for (int e = 1; e < 8; e++) mx = fmaxf(mx, l[e]);
        float s = 0.f;
        #pragma unroll
        for (int e = 0; e < 8; e++) { p[e] = expf(l[e] - mx); s += p[e]; }
        float inv_s = 1.f / s;
        #pragma unroll
        for (int e = 0; e < 8; e++) p[e] *= inv_s;
        int i1 = 0; float p1 = p[0];
        #pragma unroll
        for (int e = 1; e < 8; e++) if (p[e] > p1) { p1 = p[e]; i1 = e; }
        int i2 = -1; float p2 = -1.f;
        #pragma unroll
        for (int e = 0; e < 8; e++) if (e != i1 && p[e] > p2) { p2 = p[e]; i2 = e; }
        float inv = 1.f / (p1 + p2);
        tk_e[2 * t] = i1; tk_e[2 * t + 1] = i2;
        tk_w[2 * t] = p1 * inv; tk_w[2 * t + 1] = p2 * inv;
        atomicAdd(&counts[i1], 1);
        atomicAdd(&counts[i2], 1);
    }
}

__global__ void scan_kernel(const int* __restrict__ counts,
                            int* __restrict__ offs, int* __restrict__ cursors)
{
    if (threadIdx.x == 0) {
        int o = 0;
        for (int e = 0; e < EE; e++) { offs[e] = o; o += counts[e]; }
        offs[EE] = o;
    }
    if (threadIdx.x < EE) cursors[threadIdx.x] = 0;
}

__global__ void scatter_kernel(const int* __restrict__ tk_e,
                               const float* __restrict__ tk_w,
                               const int* __restrict__ offs,
                               int* __restrict__ cursors,
                               int* __restrict__ ent_tok,
                               float* __restrict__ ent_w)
{
    int t = blockIdx.x * blockDim.x + threadIdx.x;
    if (t >= NTOK) return;
    for (int s = 0; s < 2; s++) {
        int e = tk_e[2 * t + s];
        int pos = atomicAdd(&cursors[e], 1);
        int idx = offs[e] + pos;
        ent_tok[idx] = t;
        ent_w[idx] = tk_w[2 * t + s];
    }
}

// gather x rows into packed bf16 Xg [TOT][DD]
__global__ __launch_bounds__(256) void gather_kernel(
    const float* __restrict__ x, const int* __restrict__ ent_tok,
    u16* __restrict__ Xg)
{
    int row = blockIdx.x;
    int t = ent_tok[row];
    const float4* src = (const float4*)(x + (size_t)t * DD);
    ushort4* dst = (ushort4*)(Xg + (size_t)row * DD);
    float4 v = src[threadIdx.x];
    ushort4 o;
    o.x = f2bf(v.x); o.y = f2bf(v.y); o.z = f2bf(v.z); o.w = f2bf(v.w);
    dst[threadIdx.x] = o;
}

// in: [E][R][C] fp32 row-major -> out: [E][C][R] bf16 (transposed)
__global__ __launch_bounds__(256) void transpose_convert(
    const float* __restrict__ in, u16* __restrict__ out, int R, int C)
{
    __shared__ float tile[32][33];
    int e = blockIdx.z;
    const float* src = in + (size_t)e * R * C;
    u16* dst = out + (size_t)e * R * C;
    int c0 = blockIdx.x * 32, r0 = blockIdx.y * 32;
    int tx = threadIdx.x, ty = threadIdx.y;
    #pragma unroll
    for (int i = 0; i < 4; i++)
        tile[ty + i * 8][tx] = src[(size_t)(r0 + ty + i * 8) * C + c0 + tx];
    __syncthreads();
    #pragma unroll
    for (int i = 0; i < 4; i++)
        dst[(size_t)(c0 + ty + i * 8) * R + r0 + tx] = f2bf(tile[tx][ty + i * 8]);
}

// ---------------- grouped GEMM, 128x128 tile, 4 waves, BK=32 ----------------
// A: packed rows [TOT][KD] bf16. Wt: [E][ND][KD] bf16 (pre-transposed).
// EPI 0: OB = bf16(acc + b)            (H1)
// EPI 1: OB = bf16(silu(acc + b))      (A2)
// EPI 2: out[tok][col] += w*(acc + b)  (final, atomic)
template<int KD, int ND, int EPI>
__global__ __launch_bounds__(256, 2) void gemm_kernel(
    const u16* __restrict__ A, const u16* __restrict__ Wt,
    const float* __restrict__ bias, u16* __restrict__ OB,
    float* __restrict__ out, const int* __restrict__ offs,
    const int* __restrict__ ent_tok, const float* __restrict__ ent_w)
{
    int e = blockIdx.z;
    int mlo = offs[e], mhi = offs[e + 1];
    int m0 = mlo + blockIdx.y * 128;
    if (m0 >= mhi) return;
    int n0 = blockIdx.x * 128;

    __shared__ __align__(16) u16 lA[128 * 32];
    __shared__ __align__(16) u16 lB[128 * 32];

    int tid = threadIdx.x;
    int lane = tid & 63;
    int wave = tid >> 6;
    int wm = wave >> 1, wn = wave & 1;

    int sr = tid >> 2;          // 0..63: staged row within 64-row half
    int sk = (tid & 3) * 8;     // k-chunk offset (elems)

    f32x4 acc[4][4];
    #pragma unroll
    for (int i = 0; i < 4; i++)
        #pragma unroll
        for (int j = 0; j < 4; j++) acc[i][j] = f32x4{0.f, 0.f, 0.f, 0.f};

    const u16* wbase = Wt + (size_t)e * ND * KD;

    uint4 ra[2], rb[2];
    #pragma unroll
    for (int j = 0; j < 2; j++) {
        int ar = m0 + j * 64 + sr; ar = ar < mhi ? ar : mhi - 1;
        ra[j] = *(const uint4*)(A + (size_t)ar * KD + sk);
        int brw = n0 + j * 64 + sr;
        rb[j] = *(const uint4*)(wbase + (size_t)brw * KD + sk);
    }

    for (int k0 = 0; k0 < KD; k0 += 32) {
        __syncthreads();                      // prior compute done
        #pragma unroll
        for (int j = 0; j < 2; j++) {
            *(uint4*)(lA + (j * 64 + sr) * 32 + sk) = ra[j];
            *(uint4*)(lB + (j * 64 + sr) * 32 + sk) = rb[j];
        }
        __syncthreads();                      // tile visible
        int k1 = k0 + 32;
        if (k1 < KD) {                        // prefetch next tile into regs
            #pragma unroll
            for (int j = 0; j < 2; j++) {
                int ar = m0 + j * 64 + sr; ar = ar < mhi ? ar : mhi - 1;
                ra[j] = *(const uint4*)(A + (size_t)ar * KD + k1 + sk);
                int brw = n0 + j * 64 + sr;
                rb[j] = *(const uint4*)(wbase + (size_t)brw * KD + k1 + sk);
            }
        }
        u16x8 af[4], bf[4];
        #pragma unroll
        for (int m = 0; m < 4; m++)
            af[m] = *(const u16x8*)(lA + (wm * 64 + m * 16 + (lane & 15)) * 32 + (lane >> 4) * 8);
        #pragma unroll
        for (int n = 0; n < 4; n++)
            bf[n] = *(const u16x8*)(lB + (wn * 64 + n * 16 + (lane & 15)) * 32 + (lane >> 4) * 8);
        #pragma unroll
        for (int m = 0; m < 4; m++)
            #pragma unroll
            for (int n = 0; n < 4; n++)
                mfma_16x16x32(acc[m][n], af[m], bf[n]);
    }

    const float* bvec = bias + (size_t)e * ND;
    #pragma unroll
    for (int m = 0; m < 4; m++) {
        #pragma unroll
        for (int r = 0; r < 4; r++) {
            int row = m0 + wm * 64 + m * 16 + (lane >> 4) * 4 + r;
            if (row >= mhi) continue;
            if (EPI == 2) {
                int tok = ent_tok[row];
                float w = ent_w[row];
                #pragma unroll
                for (int n = 0; n < 4; n++) {
                    int col = n0 + wn * 64 + n * 16 + (lane & 15);
                    float v = acc[m][n][r] + bvec[col];
                    atomicAdd(&out[(size_t)tok * ND + col], w * v);
                }
            } else {
                #pragma unroll
                for (int n = 0; n < 4; n++) {
                    int col = n0 + wn * 64 + n * 16 + (lane & 15);
                    float v = acc[m][n][r] + bvec[col];
                    if (EPI == 1) v = v / (1.f + expf(-v));   // silu
                    OB[(size_t)row * ND + col] = f2bf(v);
                }
            }
        }
    }
}

extern "C" void kernel_launch(void* const* d_in, const int* in_sizes, int n_in,
                              void* d_out, int out_size, void* d_ws, size_t ws_size,
                              hipStream_t stream) {
    const float* x  = (const float*)d_in[0];
    const float* Wr = (const float*)d_in[1];
    const float* br = (const float*)d_in[2];
    const float* W1 = (const float*)d_in[3];
    const float* b1 = (const float*)d_in[4];
    const float* W2 = (const float*)d_in[5];
    const float* b2 = (const float*)d_in[6];
    const float* W3 = (const float*)d_in[7];
    const float* b3 = (const float*)d_in[8];
    float* out = (float*)d_out;

    char* ws = (char*)d_ws;
    size_t off = 0;
    auto alloc = [&](size_t bytes) {
        char* p = ws + off;
        off = (off + bytes + 255) & ~(size_t)255;
        return p;
    };
    int*   ctrl    = (int*)alloc(256);  // counts[8] | cursors[8] | offs[9]
    int*   counts  = ctrl;
    int*   cursors = ctrl + 8;
    int*   offs    = ctrl + 16;
    int*   tk_e    = (int*)  alloc((size_t)NTOK * 2 * sizeof(int));
    float* tk_w    = (float*)alloc((size_t)NTOK * 2 * sizeof(float));
    int*   ent_tok = (int*)  alloc((size_t)TOT * sizeof(int));
    float* ent_w   = (float*)alloc((size_t)TOT * sizeof(float));
    u16*   Xg      = (u16*)  alloc((size_t)TOT * DD * 2);
    u16*   H1      = (u16*)  alloc((size_t)TOT * HH * 2);
    u16*   A2      = (u16*)  alloc((size_t)TOT * HH * 2);
    u16*   W1t     = (u16*)  alloc((size_t)EE * HH * DD * 2);
    u16*   W2t     = (u16*)  alloc((size_t)EE * HH * HH * 2);
    u16*   W3t     = (u16*)  alloc((size_t)EE * DD * HH * 2);

    hipMemsetAsync(ctrl, 0, 256, stream);
    hipMemsetAsync(out, 0, (size_t)NTOK * DD * sizeof(float), stream);

    dim3 tb(32, 8);
    transpose_convert<<<dim3(HH / 32, DD / 32, EE), tb, 0, stream>>>(W1, W1t, DD, HH);
    transpose_convert<<<dim3(HH / 32, HH / 32, EE), tb, 0, stream>>>(W2, W2t, HH, HH);
    transpose_convert<<<dim3(DD / 32, HH / 32, EE), tb, 0, stream>>>(W3, W3t, HH, DD);

    router_kernel<<<NTOK / 4, 256, 0, stream>>>(x, Wr, br, tk_e, tk_w, counts);
    scan_kernel<<<1, 64, 0, stream>>>(counts, offs, cursors);
    scatter_kernel<<<(NTOK + 255) / 256, 256, 0, stream>>>(tk_e, tk_w, offs, cursors, ent_tok, ent_w);
    gather_kernel<<<TOT, 256, 0, stream>>>(x, ent_tok, Xg);

    gemm_kernel<DD, HH, 0><<<dim3(HH / 128, 64, EE), 256, 0, stream>>>(
        Xg, W1t, b1, H1, nullptr, offs, nullptr, nullptr);
    gemm_kernel<HH, HH, 1><<<dim3(HH / 128, 64, EE), 256, 0, stream>>>(
        H1, W2t, b2, A2, nullptr, offs, nullptr, nullptr);
    gemm_kernel<HH, DD, 2><<<dim3(DD / 128, 64, EE), 256, 0, stream>>>(
        A2, W3t, b3, nullptr, out, offs, ent_tok, ent_w);
}

// Round 2
// 903.946 us; speedup vs baseline: 2.1449x; 2.1449x over previous
//
#include <hip/hip_runtime.h>

#define BB 4
#define SS 2048
#define DD 1024
#define EE 8
#define HH 2048
#define NTOK (BB*SS)   // 8192 tokens
#define TOT  (NTOK*2)  // 16384 token-slots (top-2)

typedef unsigned short u16;
typedef short s16x8 __attribute__((ext_vector_type(8)));   // 8 bf16 (4 VGPRs)
typedef float f32x4 __attribute__((ext_vector_type(4)));   // 4 fp32 acc

typedef __attribute__((address_space(1))) const void gvoid;
typedef __attribute__((address_space(3))) void lvoid;

__device__ inline u16 f2bf(float f) {
    union { float f; unsigned u; } v; v.f = f;
    unsigned r = v.u + 0x7FFFu + ((v.u >> 16) & 1u);   // RNE
    return (u16)(r >> 16);
}

// async global->LDS, 16B per lane. LDS dest is wave-uniform base + lane*16;
// global src is per-lane. (m97 pattern; dest must be linear/contiguous.)
__device__ inline void gload_lds16(const void* g, void* l) {
    __builtin_amdgcn_global_load_lds((gvoid*)(uintptr_t)g,
                                     (lvoid*)(unsigned)(uintptr_t)l, 16, 0, 0);
}

// ---------------- router: fp32 logits, softmax, top-2, renorm ----------------
__global__ __launch_bounds__(256) void router_kernel(
    const float* __restrict__ x, const float* __restrict__ Wr,
    const float* __restrict__ br, int* __restrict__ tk_e,
    float* __restrict__ tk_w, int* __restrict__ counts)
{
    int wave = threadIdx.x >> 6, lane = threadIdx.x & 63;
    int t = blockIdx.x * 4 + wave;
    const float* xr = x + (size_t)t * DD;
    float acc[8];
    #pragma unroll
    for (int e = 0; e < 8; e++) acc[e] = 0.f;
    #pragma unroll
    for (int c = 0; c < 4; c++) {
        float4 v = *(const float4*)(xr + c * 256 + lane * 4);
        int dbase = c * 256 + lane * 4;
        #pragma unroll
        for (int q = 0; q < 4; q++) {
            float xv = (q == 0) ? v.x : (q == 1) ? v.y : (q == 2) ? v.z : v.w;
            const float4* wr = (const float4*)(Wr + (size_t)(dbase + q) * 8);
            float4 w0 = wr[0], w1 = wr[1];
            acc[0] += xv * w0.x; acc[1] += xv * w0.y;
            acc[2] += xv * w0.z; acc[3] += xv * w0.w;
            acc[4] += xv * w1.x; acc[5] += xv * w1.y;
            acc[6] += xv * w1.z; acc[7] += xv * w1.w;
        }
    }
    #pragma unroll
    for (int off = 32; off > 0; off >>= 1)
        #pragma unroll
        for (int e = 0; e < 8; e++) acc[e] += __shfl_xor(acc[e], off, 64);

    if (lane == 0) {
        float l[8], p[8];
        #pragma unroll
        for (int e = 0; e < 8; e++) l[e] = acc[e] + br[e];
        float mx = l[0];
        #pragma unroll
        for (int e = 1; e < 8; e++) mx = fmaxf(mx, l[e]);
        float s = 0.f;
        #pragma unroll
        for (int e = 0; e < 8; e++) { p[e] = expf(l[e] - mx); s += p[e]; }
        float inv_s = 1.f / s;
        #pragma unroll
        for (int e = 0; e < 8; e++) p[e] *= inv_s;
        int i1 = 0; float p1 = p[0];
        #pragma unroll
        for (int e = 1; e < 8; e++) if (p[e] > p1) { p1 = p[e]; i1 = e; }
        int i2 = -1; float p2 = -1.f;
        #pragma unroll
        for (int e = 0; e < 8; e++) if (e != i1 && p[e] > p2) { p2 = p[e]; i2 = e; }
        float inv = 1.f / (p1 + p2);
        tk_e[2 * t] = i1; tk_e[2 * t + 1] = i2;
        tk_w[2 * t] = p1 * inv; tk_w[2 * t + 1] = p2 * inv;
        atomicAdd(&counts[i1], 1);
        atomicAdd(&counts[i2], 1);
    }
}

__global__ void scan_kernel(const int* __restrict__ counts,
                            int* __restrict__ offs, int* __restrict__ cursors)
{
    if (threadIdx.x == 0) {
        int o = 0;
        for (int e = 0; e < EE; e++) { offs[e] = o; o += counts[e]; }
        offs[EE] = o;
    }
    if (threadIdx.x < EE) cursors[threadIdx.x] = 0;
}

__global__ void scatter_kernel(const int* __restrict__ tk_e,
                               const float* __restrict__ tk_w,
                               const int* __restrict__ offs,
                               int* __restrict__ cursors,
                               int* __restrict__ ent_tok,
                               float* __restrict__ ent_w)
{
    int t = blockIdx.x * blockDim.x + threadIdx.x;
    if (t >= NTOK) return;
    for (int s = 0; s < 2; s++) {
        int e = tk_e[2 * t + s];
        int pos = atomicAdd(&cursors[e], 1);
        int idx = offs[e] + pos;
        ent_tok[idx] = t;
        ent_w[idx] = tk_w[2 * t + s];
    }
}

// gather x rows into packed bf16 Xg [TOT][DD]
__global__ __launch_bounds__(256) void gather_kernel(
    const float* __restrict__ x, const int* __restrict__ ent_tok,
    u16* __restrict__ Xg)
{
    int row = blockIdx.x;
    int t = ent_tok[row];
    const float4* src = (const float4*)(x + (size_t)t * DD);
    ushort4* dst = (ushort4*)(Xg + (size_t)row * DD);
    float4 v = src[threadIdx.x];
    ushort4 o;
    o.x = f2bf(v.x); o.y = f2bf(v.y); o.z = f2bf(v.z); o.w = f2bf(v.w);
    dst[threadIdx.x] = o;
}

// in: [E][R][C] fp32 row-major -> out: [E][C][R] bf16 (transposed)
__global__ __launch_bounds__(256) void transpose_convert(
    const float* __restrict__ in, u16* __restrict__ out, int R, int C)
{
    __shared__ float tile[32][33];
    int e = blockIdx.z;
    const float* src = in + (size_t)e * R * C;
    u16* dst = out + (size_t)e * R * C;
    int c0 = blockIdx.x * 32, r0 = blockIdx.y * 32;
    int tx = threadIdx.x, ty = threadIdx.y;
    #pragma unroll
    for (int i = 0; i < 4; i++)
        tile[ty + i * 8][tx] = src[(size_t)(r0 + ty + i * 8) * C + c0 + tx];
    __syncthreads();
    #pragma unroll
    for (int i = 0; i < 4; i++)
        dst[(size_t)(c0 + ty + i * 8) * R + r0 + tx] = f2bf(tile[tx][ty + i * 8]);
}

// ---------------- grouped GEMM, m97 structure ----------------
// 128x128 tile, 4 waves (2x2), BK=32, global_load_lds staging, builtin MFMA.
// A: packed rows [TOT][KD] bf16. Wt: [E][ND][KD] bf16 (pre-transposed).
// EPI 0: OB = bf16(acc + b)            (H1)
// EPI 1: OB = bf16(silu(acc + b))      (A2)
// EPI 2: out[tok][col] += w*(acc + b)  (final, atomic)
template<int KD, int ND, int EPI>
__global__ __launch_bounds__(256) void gemm_kernel(
    const u16* __restrict__ A, const u16* __restrict__ Wt,
    const float* __restrict__ bias, u16* __restrict__ OB,
    float* __restrict__ out, const int* __restrict__ offs,
    const int* __restrict__ ent_tok, const float* __restrict__ ent_w)
{
    int e = blockIdx.z;
    int mlo = offs[e], mhi = offs[e + 1];
    int m0 = mlo + blockIdx.y * 128;
    if (m0 >= mhi) return;
    int n0 = blockIdx.x * 128;

    __shared__ __align__(16) u16 lA[128 * 32];   // row-major [128][32], linear
    __shared__ __align__(16) u16 lB[128 * 32];

    int tid = threadIdx.x;
    int lane = tid & 63;
    int wave = tid >> 6;
    int wm = wave >> 1, wn = wave & 1;

    // staging: wave w fills 1KB chunks {2w, 2w+1} of lA and lB.
    // chunk c covers rows 16c..16c+15; lane l -> row 16c+(l>>2), k-elems (l&3)*8
    int c0 = wave * 2;
    int lrow = lane >> 2;
    int lk = (lane & 3) * 8;
    int ar0 = m0 + c0 * 16 + lrow;       if (ar0 >= mhi) ar0 = mhi - 1;
    int ar1 = m0 + c0 * 16 + 16 + lrow;  if (ar1 >= mhi) ar1 = mhi - 1;
    const u16* gA0 = A + (size_t)ar0 * KD + lk;
    const u16* gA1 = A + (size_t)ar1 * KD + lk;
    const u16* wb = Wt + (size_t)e * ND * KD;
    const u16* gB0 = wb + (size_t)(n0 + c0 * 16 + lrow) * KD + lk;
    const u16* gB1 = wb + (size_t)(n0 + c0 * 16 + 16 + lrow) * KD + lk;
    u16* sA0 = lA + c0 * 512;   // wave-uniform LDS chunk bases
    u16* sB0 = lB + c0 * 512;

    f32x4 acc[4][4];
    #pragma unroll
    for (int i = 0; i < 4; i++)
        #pragma unroll
        for (int j = 0; j < 4; j++) acc[i][j] = f32x4{0.f, 0.f, 0.f, 0.f};

    for (int k0 = 0; k0 < KD; k0 += 32) {
        __syncthreads();                  // prior tile's reads done
        gload_lds16(gA0 + k0, sA0);
        gload_lds16(gA1 + k0, sA0 + 512);
        gload_lds16(gB0 + k0, sB0);
        gload_lds16(gB1 + k0, sB0 + 512);
        __syncthreads();                  // drains vmcnt(0): tile visible

        s16x8 af[4], bf[4];
        #pragma unroll
        for (int m = 0; m < 4; m++)
            af[m] = *(const s16x8*)(lA + (wm * 64 + m * 16 + (lane & 15)) * 32 + (lane >> 4) * 8);
        #pragma unroll
        for (int n = 0; n < 4; n++)
            bf[n] = *(const s16x8*)(lB + (wn * 64 + n * 16 + (lane & 15)) * 32 + (lane >> 4) * 8);
        #pragma unroll
        for (int m = 0; m < 4; m++)
            #pragma unroll
            for (int n = 0; n < 4; n++)
                acc[m][n] = __builtin_amdgcn_mfma_f32_16x16x32_bf16(af[m], bf[n], acc[m][n], 0, 0, 0);
    }

    const float* bvec = bias + (size_t)e * ND;
    #pragma unroll
    for (int m = 0; m < 4; m++) {
        #pragma unroll
        for (int r = 0; r < 4; r++) {
            int row = m0 + wm * 64 + m * 16 + (lane >> 4) * 4 + r;
            if (row >= mhi) continue;
            if (EPI == 2) {
                int tok = ent_tok[row];
                float w = ent_w[row];
                #pragma unroll
                for (int n = 0; n < 4; n++) {
                    int col = n0 + wn * 64 + n * 16 + (lane & 15);
                    float v = acc[m][n][r] + bvec[col];
                    atomicAdd(&out[(size_t)tok * ND + col], w * v);
                }
            } else {
                #pragma unroll
                for (int n = 0; n < 4; n++) {
                    int col = n0 + wn * 64 + n * 16 + (lane & 15);
                    float v = acc[m][n][r] + bvec[col];
                    if (EPI == 1) v = v / (1.f + expf(-v));   // silu
                    OB[(size_t)row * ND + col] = f2bf(v);
                }
            }
        }
    }
}

extern "C" void kernel_launch(void* const* d_in, const int* in_sizes, int n_in,
                              void* d_out, int out_size, void* d_ws, size_t ws_size,
                              hipStream_t stream) {
    const float* x  = (const float*)d_in[0];
    const float* Wr = (const float*)d_in[1];
    const float* br = (const float*)d_in[2];
    const float* W1 = (const float*)d_in[3];
    const float* b1 = (const float*)d_in[4];
    const float* W2 = (const float*)d_in[5];
    const float* b2 = (const float*)d_in[6];
    const float* W3 = (const float*)d_in[7];
    const float* b3 = (const float*)d_in[8];
    float* out = (float*)d_out;

    char* ws = (char*)d_ws;
    size_t off = 0;
    auto alloc = [&](size_t bytes) {
        char* p = ws + off;
        off = (off + bytes + 255) & ~(size_t)255;
        return p;
    };
    int*   ctrl    = (int*)alloc(256);  // counts[8] | cursors[8] | offs[9]
    int*   counts  = ctrl;
    int*   cursors = ctrl + 8;
    int*   offs    = ctrl + 16;
    int*   tk_e    = (int*)  alloc((size_t)NTOK * 2 * sizeof(int));
    float* tk_w    = (float*)alloc((size_t)NTOK * 2 * sizeof(float));
    int*   ent_tok = (int*)  alloc((size_t)TOT * sizeof(int));
    float* ent_w   = (float*)alloc((size_t)TOT * sizeof(float));
    u16*   Xg      = (u16*)  alloc((size_t)TOT * DD * 2);
    u16*   H1      = (u16*)  alloc((size_t)TOT * HH * 2);
    u16*   A2      = (u16*)  alloc((size_t)TOT * HH * 2);
    u16*   W1t     = (u16*)  alloc((size_t)EE * HH * DD * 2);
    u16*   W2t     = (u16*)  alloc((size_t)EE * HH * HH * 2);
    u16*   W3t     = (u16*)  alloc((size_t)EE * DD * HH * 2);

    hipMemsetAsync(ctrl, 0, 256, stream);
    hipMemsetAsync(out, 0, (size_t)NTOK * DD * sizeof(float), stream);

    dim3 tb(32, 8);
    transpose_convert<<<dim3(HH / 32, DD / 32, EE), tb, 0, stream>>>(W1, W1t, DD, HH);
    transpose_convert<<<dim3(HH / 32, HH / 32, EE), tb, 0, stream>>>(W2, W2t, HH, HH);
    transpose_convert<<<dim3(DD / 32, HH / 32, EE), tb, 0, stream>>>(W3, W3t, HH, DD);

    router_kernel<<<NTOK / 4, 256, 0, stream>>>(x, Wr, br, tk_e, tk_w, counts);
    scan_kernel<<<1, 64, 0, stream>>>(counts, offs, cursors);
    scatter_kernel<<<(NTOK + 255) / 256, 256, 0, stream>>>(tk_e, tk_w, offs, cursors, ent_tok, ent_w);
    gather_kernel<<<TOT, 256, 0, stream>>>(x, ent_tok, Xg);

    gemm_kernel<DD, HH, 0><<<dim3(HH / 128, 64, EE), 256, 0, stream>>>(
        Xg, W1t, b1, H1, nullptr, offs, nullptr, nullptr);
    gemm_kernel<HH, HH, 1><<<dim3(HH / 128, 64, EE), 256, 0, stream>>>(
        H1, W2t, b2, A2, nullptr, offs, nullptr, nullptr);
    gemm_kernel<HH, DD, 2><<<dim3(DD / 128, 64, EE), 256, 0, stream>>>(
        A2, W3t, b3, nullptr, out, offs, ent_tok, ent_w);
}

// Round 3
// 901.772 us; speedup vs baseline: 2.1501x; 1.0024x over previous
//
#include <hip/hip_runtime.h>

#define BB 4
#define SS 2048
#define DD 1024
#define EE 8
#define HH 2048
#define NTOK (BB*SS)   // 8192 tokens
#define TOT  (NTOK*2)  // 16384 token-slots (top-2)

typedef unsigned short u16;
typedef short s16x8 __attribute__((ext_vector_type(8)));   // 8 bf16 (4 VGPRs)
typedef float f32x4 __attribute__((ext_vector_type(4)));   // 4 fp32 acc

typedef __attribute__((address_space(1))) const void gvoid;
typedef __attribute__((address_space(3))) void lvoid;

__device__ inline u16 f2bf(float f) {
    union { float f; unsigned u; } v; v.f = f;
    unsigned r = v.u + 0x7FFFu + ((v.u >> 16) & 1u);   // RNE
    return (u16)(r >> 16);
}

// async global->LDS, 16B per lane. LDS dest is wave-uniform base + lane*16;
// global src is per-lane. (m97 pattern; dest must be linear/contiguous.)
__device__ inline void gload_lds16(const void* g, void* l) {
    __builtin_amdgcn_global_load_lds((gvoid*)(uintptr_t)g,
                                     (lvoid*)(unsigned)(uintptr_t)l, 16, 0, 0);
}

// ---------------- router: fp32 logits, softmax, top-2, renorm ----------------
__global__ __launch_bounds__(256) void router_kernel(
    const float* __restrict__ x, const float* __restrict__ Wr,
    const float* __restrict__ br, int* __restrict__ tk_e,
    float* __restrict__ tk_w, int* __restrict__ counts)
{
    int wave = threadIdx.x >> 6, lane = threadIdx.x & 63;
    int t = blockIdx.x * 4 + wave;
    const float* xr = x + (size_t)t * DD;
    float acc[8];
    #pragma unroll
    for (int e = 0; e < 8; e++) acc[e] = 0.f;
    #pragma unroll
    for (int c = 0; c < 4; c++) {
        float4 v = *(const float4*)(xr + c * 256 + lane * 4);
        int dbase = c * 256 + lane * 4;
        #pragma unroll
        for (int q = 0; q < 4; q++) {
            float xv = (q == 0) ? v.x : (q == 1) ? v.y : (q == 2) ? v.z : v.w;
            const float4* wr = (const float4*)(Wr + (size_t)(dbase + q) * 8);
            float4 w0 = wr[0], w1 = wr[1];
            acc[0] += xv * w0.x; acc[1] += xv * w0.y;
            acc[2] += xv * w0.z; acc[3] += xv * w0.w;
            acc[4] += xv * w1.x; acc[5] += xv * w1.y;
            acc[6] += xv * w1.z; acc[7] += xv * w1.w;
        }
    }
    #pragma unroll
    for (int off = 32; off > 0; off >>= 1)
        #pragma unroll
        for (int e = 0; e < 8; e++) acc[e] += __shfl_xor(acc[e], off, 64);

    if (lane == 0) {
        float l[8], p[8];
        #pragma unroll
        for (int e = 0; e < 8; e++) l[e] = acc[e] + br[e];
        float mx = l[0];
        #pragma unroll
        for (int e = 1; e < 8; e++) mx = fmaxf(mx, l[e]);
        float s = 0.f;
        #pragma unroll
        for (int e = 0; e < 8; e++) { p[e] = expf(l[e] - mx); s += p[e]; }
        float inv_s = 1.f / s;
        #pragma unroll
        for (int e = 0; e < 8; e++) p[e] *= inv_s;
        int i1 = 0; float p1 = p[0];
        #pragma unroll
        for (int e = 1; e < 8; e++) if (p[e] > p1) { p1 = p[e]; i1 = e; }
        int i2 = -1; float p2 = -1.f;
        #pragma unroll
        for (int e = 0; e < 8; e++) if (e != i1 && p[e] > p2) { p2 = p[e]; i2 = e; }
        float inv = 1.f / (p1 + p2);
        tk_e[2 * t] = i1; tk_e[2 * t + 1] = i2;
        tk_w[2 * t] = p1 * inv; tk_w[2 * t + 1] = p2 * inv;
        atomicAdd(&counts[i1], 1);
        atomicAdd(&counts[i2], 1);
    }
}

__global__ void scan_kernel(const int* __restrict__ counts,
                            int* __restrict__ offs, int* __restrict__ cursors)
{
    if (threadIdx.x == 0) {
        int o = 0;
        for (int e = 0; e < EE; e++) { offs[e] = o; o += counts[e]; }
        offs[EE] = o;
    }
    if (threadIdx.x < EE) cursors[threadIdx.x] = 0;
}

__global__ void scatter_kernel(const int* __restrict__ tk_e,
                               const float* __restrict__ tk_w,
                               const int* __restrict__ offs,
                               int* __restrict__ cursors,
                               int* __restrict__ ent_tok,
                               float* __restrict__ ent_w)
{
    int t = blockIdx.x * blockDim.x + threadIdx.x;
    if (t >= NTOK) return;
    for (int s = 0; s < 2; s++) {
        int e = tk_e[2 * t + s];
        int pos = atomicAdd(&cursors[e], 1);
        int idx = offs[e] + pos;
        ent_tok[idx] = t;
        ent_w[idx] = tk_w[2 * t + s];
    }
}

// gather x rows into packed bf16 Xg [TOT][DD]
__global__ __launch_bounds__(256) void gather_kernel(
    const float* __restrict__ x, const int* __restrict__ ent_tok,
    u16* __restrict__ Xg)
{
    int row = blockIdx.x;
    int t = ent_tok[row];
    const float4* src = (const float4*)(x + (size_t)t * DD);
    ushort4* dst = (ushort4*)(Xg + (size_t)row * DD);
    float4 v = src[threadIdx.x];
    ushort4 o;
    o.x = f2bf(v.x); o.y = f2bf(v.y); o.z = f2bf(v.z); o.w = f2bf(v.w);
    dst[threadIdx.x] = o;
}

// in: [E][R][C] fp32 row-major -> out: [E][C][R] bf16 (transposed)
__global__ __launch_bounds__(256) void transpose_convert(
    const float* __restrict__ in, u16* __restrict__ out, int R, int C)
{
    __shared__ float tile[32][33];
    int e = blockIdx.z;
    const float* src = in + (size_t)e * R * C;
    u16* dst = out + (size_t)e * R * C;
    int c0 = blockIdx.x * 32, r0 = blockIdx.y * 32;
    int tx = threadIdx.x, ty = threadIdx.y;
    #pragma unroll
    for (int i = 0; i < 4; i++)
        tile[ty + i * 8][tx] = src[(size_t)(r0 + ty + i * 8) * C + c0 + tx];
    __syncthreads();
    #pragma unroll
    for (int i = 0; i < 4; i++)
        dst[(size_t)(c0 + ty + i * 8) * R + r0 + tx] = f2bf(tile[tx][ty + i * 8]);
}

// ---------------- grouped GEMM, m97 structure ----------------
// 128x128 tile, 4 waves (2x2), BK=32, global_load_lds staging, builtin MFMA.
// A: packed rows [TOT][KD] bf16. Wt: [E][ND][KD] bf16 (pre-transposed).
// EPI 0: OB = bf16(acc + b)            (H1)
// EPI 1: OB = bf16(silu(acc + b))      (A2)
// EPI 2: out[tok][col] += w*(acc + b)  (final, atomic)
template<int KD, int ND, int EPI>
__global__ __launch_bounds__(256) void gemm_kernel(
    const u16* __restrict__ A, const u16* __restrict__ Wt,
    const float* __restrict__ bias, u16* __restrict__ OB,
    float* __restrict__ out, const int* __restrict__ offs,
    const int* __restrict__ ent_tok, const float* __restrict__ ent_w)
{
    int e = blockIdx.z;
    int mlo = offs[e], mhi = offs[e + 1];
    int m0 = mlo + blockIdx.y * 128;
    if (m0 >= mhi) return;
    int n0 = blockIdx.x * 128;

    __shared__ __align__(16) u16 lA[128 * 32];   // row-major [128][32], linear
    __shared__ __align__(16) u16 lB[128 * 32];

    int tid = threadIdx.x;
    int lane = tid & 63;
    int wave = tid >> 6;
    int wm = wave >> 1, wn = wave & 1;

    // staging: wave w fills 1KB chunks {2w, 2w+1} of lA and lB.
    // chunk c covers rows 16c..16c+15; lane l -> row 16c+(l>>2), k-elems (l&3)*8
    int c0 = wave * 2;
    int lrow = lane >> 2;
    int lk = (lane & 3) * 8;
    int ar0 = m0 + c0 * 16 + lrow;       if (ar0 >= mhi) ar0 = mhi - 1;
    int ar1 = m0 + c0 * 16 + 16 + lrow;  if (ar1 >= mhi) ar1 = mhi - 1;
    const u16* gA0 = A + (size_t)ar0 * KD + lk;
    const u16* gA1 = A + (size_t)ar1 * KD + lk;
    const u16* wb = Wt + (size_t)e * ND * KD;
    const u16* gB0 = wb + (size_t)(n0 + c0 * 16 + lrow) * KD + lk;
    const u16* gB1 = wb + (size_t)(n0 + c0 * 16 + 16 + lrow) * KD + lk;
    u16* sA0 = lA + c0 * 512;   // wave-uniform LDS chunk bases
    u16* sB0 = lB + c0 * 512;

    f32x4 acc[4][4];
    #pragma unroll
    for (int i = 0; i < 4; i++)
        #pragma unroll
        for (int j = 0; j < 4; j++) acc[i][j] = f32x4{0.f, 0.f, 0.f, 0.f};

    for (int k0 = 0; k0 < KD; k0 += 32) {
        __syncthreads();                  // prior tile's reads done
        gload_lds16(gA0 + k0, sA0);
        gload_lds16(gA1 + k0, sA0 + 512);
        gload_lds16(gB0 + k0, sB0);
        gload_lds16(gB1 + k0, sB0 + 512);
        __syncthreads();                  // drains vmcnt(0): tile visible

        s16x8 af[4], bf[4];
        #pragma unroll
        for (int m = 0; m < 4; m++)
            af[m] = *(const s16x8*)(lA + (wm * 64 + m * 16 + (lane & 15)) * 32 + (lane >> 4) * 8);
        #pragma unroll
        for (int n = 0; n < 4; n++)
            bf[n] = *(const s16x8*)(lB + (wn * 64 + n * 16 + (lane & 15)) * 32 + (lane >> 4) * 8);
        #pragma unroll
        for (int m = 0; m < 4; m++)
            #pragma unroll
            for (int n = 0; n < 4; n++)
                acc[m][n] = __builtin_amdgcn_mfma_f32_16x16x32_bf16(af[m], bf[n], acc[m][n], 0, 0, 0);
    }

    const float* bvec = bias + (size_t)e * ND;
    #pragma unroll
    for (int m = 0; m < 4; m++) {
        #pragma unroll
        for (int r = 0; r < 4; r++) {
            int row = m0 + wm * 64 + m * 16 + (lane >> 4) * 4 + r;
            if (row >= mhi) continue;
            if (EPI == 2) {
                int tok = ent_tok[row];
                float w = ent_w[row];
                #pragma unroll
                for (int n = 0; n < 4; n++) {
                    int col = n0 + wn * 64 + n * 16 + (lane & 15);
                    float v = acc[m][n][r] + bvec[col];
                    atomicAdd(&out[(size_t)tok * ND + col], w * v);
                }
            } else {
                #pragma unroll
                for (int n = 0; n < 4; n++) {
                    int col = n0 + wn * 64 + n * 16 + (lane & 15);
                    float v = acc[m][n][r] + bvec[col];
                    if (EPI == 1) v = v / (1.f + expf(-v));   // silu
                    OB[(size_t)row * ND + col] = f2bf(v);
                }
            }
        }
    }
}

extern "C" void kernel_launch(void* const* d_in, const int* in_sizes, int n_in,
                              void* d_out, int out_size, void* d_ws, size_t ws_size,
                              hipStream_t stream) {
    const float* x  = (const float*)d_in[0];
    const float* Wr = (const float*)d_in[1];
    const float* br = (const float*)d_in[2];
    const float* W1 = (const float*)d_in[3];
    const float* b1 = (const float*)d_in[4];
    const float* W2 = (const float*)d_in[5];
    const float* b2 = (const float*)d_in[6];
    const float* W3 = (const float*)d_in[7];
    const float* b3 = (const float*)d_in[8];
    float* out = (float*)d_out;

    char* ws = (char*)d_ws;
    size_t off = 0;
    auto alloc = [&](size_t bytes) {
        char* p = ws + off;
        off = (off + bytes + 255) & ~(size_t)255;
        return p;
    };
    int*   ctrl    = (int*)alloc(256);  // counts[8] | cursors[8] | offs[9]
    int*   counts  = ctrl;
    int*   cursors = ctrl + 8;
    int*   offs    = ctrl + 16;
    int*   tk_e    = (int*)  alloc((size_t)NTOK * 2 * sizeof(int));
    float* tk_w    = (float*)alloc((size_t)NTOK * 2 * sizeof(float));
    int*   ent_tok = (int*)  alloc((size_t)TOT * sizeof(int));
    float* ent_w   = (float*)alloc((size_t)TOT * sizeof(float));
    u16*   Xg      = (u16*)  alloc((size_t)TOT * DD * 2);
    u16*   H1      = (u16*)  alloc((size_t)TOT * HH * 2);
    u16*   A2      = (u16*)  alloc((size_t)TOT * HH * 2);
    u16*   W1t     = (u16*)  alloc((size_t)EE * HH * DD * 2);
    u16*   W2t     = (u16*)  alloc((size_t)EE * HH * HH * 2);
    u16*   W3t     = (u16*)  alloc((size_t)EE * DD * HH * 2);

    hipMemsetAsync(ctrl, 0, 256, stream);
    hipMemsetAsync(out, 0, (size_t)NTOK * DD * sizeof(float), stream);

    dim3 tb(32, 8);
    transpose_convert<<<dim3(HH / 32, DD / 32, EE), tb, 0, stream>>>(W1, W1t, DD, HH);
    transpose_convert<<<dim3(HH / 32, HH / 32, EE), tb, 0, stream>>>(W2, W2t, HH, HH);
    transpose_convert<<<dim3(DD / 32, HH / 32, EE), tb, 0, stream>>>(W3, W3t, HH, DD);

    router_kernel<<<NTOK / 4, 256, 0, stream>>>(x, Wr, br, tk_e, tk_w, counts);
    scan_kernel<<<1, 64, 0, stream>>>(counts, offs, cursors);
    scatter_kernel<<<(NTOK + 255) / 256, 256, 0, stream>>>(tk_e, tk_w, offs, cursors, ent_tok, ent_w);
    gather_kernel<<<TOT, 256, 0, stream>>>(x, ent_tok, Xg);

    gemm_kernel<DD, HH, 0><<<dim3(HH / 128, 64, EE), 256, 0, stream>>>(
        Xg, W1t, b1, H1, nullptr, offs, nullptr, nullptr);
    gemm_kernel<HH, HH, 1><<<dim3(HH / 128, 64, EE), 256, 0, stream>>>(
        H1, W2t, b2, A2, nullptr, offs, nullptr, nullptr);
    gemm_kernel<HH, DD, 2><<<dim3(DD / 128, 64, EE), 256, 0, stream>>>(
        A2, W3t, b3, nullptr, out, offs, ent_tok, ent_w);
}